// Round 1
// baseline (93.410 us; speedup 1.0000x reference)
//
#include <hip/hip_runtime.h>
#include <stdint.h>

// Problem constants (LSHSoftmax): B=1024, D=512, N=500000, S=32768
#define B_DIM 1024
#define D_DIM 512
#define S_DIM 32768

typedef __attribute__((ext_vector_type(8))) short bf16x8;   // 8 bf16 = 4 VGPRs
typedef __attribute__((ext_vector_type(4))) float f32x4;
typedef __attribute__((ext_vector_type(8))) unsigned short u16x8;

#define AS1 __attribute__((address_space(1)))
#define AS3 __attribute__((address_space(3)))

__device__ __forceinline__ unsigned short f2bf(float f) {
  union { float f; uint32_t u; } x; x.f = f;
  uint32_t r = x.u + 0x7fffu + ((x.u >> 16) & 1u);   // RNE
  return (unsigned short)(r >> 16);
}

// Gather weight rows by sample_ids, convert f32 -> bf16. Also gather bias.
// Grid: S*64 threads, each handles 8 elements of one row.
__global__ __launch_bounds__(256) void gather_w(const float* __restrict__ W,
                                                const float* __restrict__ bias,
                                                const int* __restrict__ ids,
                                                unsigned short* __restrict__ Wg,
                                                float* __restrict__ bg) {
  int gid = blockIdx.x * 256 + threadIdx.x;  // 0 .. S*64
  int s = gid >> 6;
  int c = (gid & 63) * 8;
  int sid = ids[s];
  const float* src = W + (size_t)sid * D_DIM + c;
  float4 v0 = *(const float4*)src;
  float4 v1 = *(const float4*)(src + 4);
  u16x8 o;
  o[0] = f2bf(v0.x); o[1] = f2bf(v0.y); o[2] = f2bf(v0.z); o[3] = f2bf(v0.w);
  o[4] = f2bf(v1.x); o[5] = f2bf(v1.y); o[6] = f2bf(v1.z); o[7] = f2bf(v1.w);
  *(u16x8*)(Wg + (size_t)s * D_DIM + c) = o;
  if ((gid & 63) == 0) bg[s] = bias[sid];
}

// Convert inputs f32 -> bf16. Grid: B*D/8 threads.
__global__ __launch_bounds__(256) void conv_a(const float* __restrict__ A,
                                              unsigned short* __restrict__ Ab) {
  int gid = blockIdx.x * 256 + threadIdx.x;
  const float* src = A + (size_t)gid * 8;
  float4 v0 = *(const float4*)src;
  float4 v1 = *(const float4*)(src + 4);
  u16x8 o;
  o[0] = f2bf(v0.x); o[1] = f2bf(v0.y); o[2] = f2bf(v0.z); o[3] = f2bf(v0.w);
  o[4] = f2bf(v1.x); o[5] = f2bf(v1.y); o[6] = f2bf(v1.z); o[7] = f2bf(v1.w);
  *(u16x8*)(Ab + (size_t)gid * 8) = o;
}

// bf16 GEMM: C[m, n] = sum_k Ab[m, k] * Wg[n, k] + bg[n]
// m97-style: 128x128 tile, BK=64, 4 waves (2x2), 4x4 16x16x32 fragments per wave,
// global_load_lds width=16 staging (linear LDS, wave-uniform dest).
#define BM 128
#define BN 128
#define BK 64

__global__ __launch_bounds__(256) void gemm_bias(const unsigned short* __restrict__ Ab,
                                                 const unsigned short* __restrict__ Wg,
                                                 const float* __restrict__ bg,
                                                 float* __restrict__ out) {
  __shared__ __attribute__((aligned(16))) unsigned short sA[BM * BK];
  __shared__ __attribute__((aligned(16))) unsigned short sB[BN * BK];

  const int tid = threadIdx.x;
  const int lane = tid & 63;
  const int w = tid >> 6;          // wave 0..3
  const int wr = w >> 1;           // wave row (0..1)
  const int wc = w & 1;            // wave col (0..1)

  const int bm = blockIdx.x & 7;   // 8 row tiles
  const int bn = blockIdx.x >> 3;  // 256 col tiles
  const int m0 = bm * BM;
  const int n0 = bn * BN;

  f32x4 acc[4][4];
#pragma unroll
  for (int m = 0; m < 4; ++m)
#pragma unroll
    for (int n = 0; n < 4; ++n)
      acc[m][n] = (f32x4)0.0f;

  const int lq = lane >> 4;     // 0..3
  const int l16 = lane & 15;

  for (int kt = 0; kt < D_DIM / BK; ++kt) {
    const int k0 = kt * BK;
    // ---- stage A,B tiles into LDS (each wave: 4 issues x 1024B each per tile) ----
#pragma unroll
    for (int j = 0; j < 4; ++j) {
      const int L = w * 4096 + j * 1024 + lane * 16;  // byte offset within 16KB tile
      const int row = L >> 7;                         // tile row (128B per row)
      const int cb = L & 127;                         // byte within row
      const char* gA = (const char*)Ab + ((size_t)(m0 + row) * D_DIM + k0) * 2 + cb;
      const char* gB = (const char*)Wg + ((size_t)(n0 + row) * D_DIM + k0) * 2 + cb;
      __builtin_amdgcn_global_load_lds((const AS1 void*)gA,
                                       (AS3 void*)((char*)sA + w * 4096 + j * 1024),
                                       16, 0, 0);
      __builtin_amdgcn_global_load_lds((const AS1 void*)gB,
                                       (AS3 void*)((char*)sB + w * 4096 + j * 1024),
                                       16, 0, 0);
    }
    __syncthreads();   // drains vmcnt before barrier (compiler-inserted)

    // ---- compute: 2 K-substeps of 32, 16 MFMA each ----
#pragma unroll
    for (int kk = 0; kk < 2; ++kk) {
      const int kc = kk * 32 + lq * 8;
      bf16x8 af[4], bv[4];
#pragma unroll
      for (int m = 0; m < 4; ++m)
        af[m] = *(const bf16x8*)&sA[(wr * 64 + m * 16 + l16) * BK + kc];
#pragma unroll
      for (int n = 0; n < 4; ++n)
        bv[n] = *(const bf16x8*)&sB[(wc * 64 + n * 16 + l16) * BK + kc];
#pragma unroll
      for (int m = 0; m < 4; ++m)
#pragma unroll
        for (int n = 0; n < 4; ++n)
          acc[m][n] = __builtin_amdgcn_mfma_f32_16x16x32_bf16(af[m], bv[n], acc[m][n], 0, 0, 0);
    }
    __syncthreads();
  }

  // ---- epilogue: C[row][col] = acc + bias[col] ----
  const int lrow = lq * 4;
#pragma unroll
  for (int n = 0; n < 4; ++n) {
    const int col = n0 + wc * 64 + n * 16 + l16;
    const float bvv = bg[col];
#pragma unroll
    for (int m = 0; m < 4; ++m) {
      const int rbase = m0 + wr * 64 + m * 16 + lrow;
#pragma unroll
      for (int r = 0; r < 4; ++r) {
        out[(size_t)(rbase + r) * S_DIM + col] = acc[m][n][r] + bvv;
      }
    }
  }
}

extern "C" void kernel_launch(void* const* d_in, const int* in_sizes, int n_in,
                              void* d_out, int out_size, void* d_ws, size_t ws_size,
                              hipStream_t stream) {
  const float* inp  = (const float*)d_in[0];   // [B, D] f32
  const float* W    = (const float*)d_in[1];   // [N, D] f32
  const float* bias = (const float*)d_in[2];   // [N] f32
  const int*   ids  = (const int*)d_in[3];     // [S] int32
  float* out = (float*)d_out;                  // [B, S] f32

  // workspace layout
  unsigned short* Wg = (unsigned short*)d_ws;                            // [S, D] bf16 (32 MiB)
  unsigned short* Ab = (unsigned short*)((char*)d_ws +
                        (size_t)S_DIM * D_DIM * 2);                      // [B, D] bf16 (1 MiB)
  float* bg = (float*)((char*)d_ws +
                        (size_t)S_DIM * D_DIM * 2 + (size_t)B_DIM * D_DIM * 2); // [S] f32

  gather_w<<<S_DIM / 4, 256, 0, stream>>>(W, bias, ids, Wg, bg);
  conv_a<<<(B_DIM * D_DIM / 8) / 256, 256, 0, stream>>>(inp, Ab);

  dim3 grid((B_DIM / BM) * (S_DIM / BN));   // 8 * 256 = 2048 blocks
  gemm_bias<<<grid, 256, 0, stream>>>(Ab, Wg, bg, out);
}

// Round 2
// 75.293 us; speedup vs baseline: 1.2406x; 1.2406x over previous
//
#include <hip/hip_runtime.h>
#include <stdint.h>

// Problem constants (LSHSoftmax): B=1024, D=512, N=500000, S=32768
#define B_DIM 1024
#define D_DIM 512
#define S_DIM 32768

typedef __attribute__((ext_vector_type(8))) short bf16x8;   // 8 bf16 = 4 VGPRs
typedef __attribute__((ext_vector_type(4))) float f32x4;
typedef __attribute__((ext_vector_type(8))) unsigned short u16x8;

#define AS1 __attribute__((address_space(1)))
#define AS3 __attribute__((address_space(3)))

__device__ __forceinline__ unsigned short f2bf(float f) {
  union { float f; uint32_t u; } x; x.f = f;
  uint32_t r = x.u + 0x7fffu + ((x.u >> 16) & 1u);   // RNE
  return (unsigned short)(r >> 16);
}

// Gather weight rows by sample_ids, convert f32 -> bf16. Also gather bias.
__global__ __launch_bounds__(256) void gather_w(const float* __restrict__ W,
                                                const float* __restrict__ bias,
                                                const int* __restrict__ ids,
                                                unsigned short* __restrict__ Wg,
                                                float* __restrict__ bg) {
  int gid = blockIdx.x * 256 + threadIdx.x;  // 0 .. S*64
  int s = gid >> 6;
  int c = (gid & 63) * 8;
  int sid = ids[s];
  const float* src = W + (size_t)sid * D_DIM + c;
  float4 v0 = *(const float4*)src;
  float4 v1 = *(const float4*)(src + 4);
  u16x8 o;
  o[0] = f2bf(v0.x); o[1] = f2bf(v0.y); o[2] = f2bf(v0.z); o[3] = f2bf(v0.w);
  o[4] = f2bf(v1.x); o[5] = f2bf(v1.y); o[6] = f2bf(v1.z); o[7] = f2bf(v1.w);
  *(u16x8*)(Wg + (size_t)s * D_DIM + c) = o;
  if ((gid & 63) == 0) bg[s] = bias[sid];
}

// Convert inputs f32 -> bf16.
__global__ __launch_bounds__(256) void conv_a(const float* __restrict__ A,
                                              unsigned short* __restrict__ Ab) {
  int gid = blockIdx.x * 256 + threadIdx.x;
  const float* src = A + (size_t)gid * 8;
  float4 v0 = *(const float4*)src;
  float4 v1 = *(const float4*)(src + 4);
  u16x8 o;
  o[0] = f2bf(v0.x); o[1] = f2bf(v0.y); o[2] = f2bf(v0.z); o[3] = f2bf(v0.w);
  o[4] = f2bf(v1.x); o[5] = f2bf(v1.y); o[6] = f2bf(v1.z); o[7] = f2bf(v1.w);
  *(u16x8*)(Ab + (size_t)gid * 8) = o;
}

// ---------------------------------------------------------------------------
// GEMM: C[m,n] = sum_k Ab[m,k]*Wg[n,k] + bg[n]
// 256x128 tile, BK=64, 8 waves (4 row x 2 col), 3-buffer LDS pipeline with
// prefetch depth 2 and counted vmcnt (no drain in main loop), XOR-swizzled
// LDS (conflict-free ds_read_b128), setprio around MFMA, XCD block swizzle.
// ---------------------------------------------------------------------------
#define BM 256
#define BN 128
#define BK 64
#define NKT (D_DIM / BK)          // 8 K-tiles
#define ABYTES (BM * BK * 2)      // 32768
#define BBYTES (BN * BK * 2)      // 16384
#define BUFBYTES (ABYTES + BBYTES) // 49152; 3 buffers = 144 KiB LDS

__global__ __launch_bounds__(512, 2) void gemm_bias(const unsigned short* __restrict__ Ab,
                                                    const unsigned short* __restrict__ Wg,
                                                    const float* __restrict__ bg,
                                                    float* __restrict__ out) {
  __shared__ __attribute__((aligned(16))) char lds[3 * BUFBYTES];

  const int tid = threadIdx.x;
  const int lane = tid & 63;
  const int w = tid >> 6;          // wave 0..7
  const int wr = w >> 1;           // wave row 0..3 (64 rows each)
  const int wc = w & 1;            // wave col 0..1 (64 cols each)
  const int lq = lane >> 4;        // 0..3
  const int l16 = lane & 15;

  // XCD-aware swizzle: 1024 blocks, 8 XCDs, 128 contiguous tiles per XCD.
  int id = ((blockIdx.x & 7) << 7) | (blockIdx.x >> 3);
  const int bm = id & 3;           // 4 row tiles (fastest: share B panel)
  const int bn = id >> 2;          // 256 col tiles
  const int m0 = bm * BM;
  const int n0 = bn * BN;

  f32x4 acc[4][4];
#pragma unroll
  for (int m = 0; m < 4; ++m)
#pragma unroll
    for (int n = 0; n < 4; ++n)
      acc[m][n] = (f32x4)0.0f;

  // Stage K-tile kt into buffer kt%3. Linear LDS dest (wave-uniform base),
  // inverse-swizzled global source: physical byte P holds logical byte
  // S(P) = P ^ (((P>>7)&7)<<4)  (swizzle within each 128B row, involution).
  auto stage = [&](int kt) {
    char* ldsA = lds + (kt % 3) * BUFBYTES;
    char* ldsB = ldsA + ABYTES;
#pragma unroll
    for (int j = 0; j < 4; ++j) {               // A: 32 KB = 8 waves x 4 x 1KB
      const int Pb = j * 8192 + w * 1024;       // wave-uniform
      const int P = Pb + lane * 16;
      const int L = P ^ (((P >> 7) & 7) << 4);  // logical byte in tile
      const char* src = (const char*)Ab +
          (size_t)(m0 + (L >> 7)) * (D_DIM * 2) + kt * (BK * 2) + (L & 127);
      __builtin_amdgcn_global_load_lds((const AS1 void*)src,
                                       (AS3 void*)(ldsA + Pb), 16, 0, 0);
    }
#pragma unroll
    for (int j = 0; j < 2; ++j) {               // B: 16 KB = 8 waves x 2 x 1KB
      const int Pb = j * 8192 + w * 1024;
      const int P = Pb + lane * 16;
      const int L = P ^ (((P >> 7) & 7) << 4);
      const char* src = (const char*)Wg +
          (size_t)(n0 + (L >> 7)) * (D_DIM * 2) + kt * (BK * 2) + (L & 127);
      __builtin_amdgcn_global_load_lds((const AS1 void*)src,
                                       (AS3 void*)(ldsB + Pb), 16, 0, 0);
    }
  };

  stage(0);
  stage(1);

  const int swz = (l16 & 7) << 4;   // row&7 == l16&7 for all fragment rows

#pragma unroll
  for (int kt = 0; kt < NKT; ++kt) {
    // Prefetch depth 2; counted vmcnt: 6 gload/wave per stage; allow the
    // newest 12 (stages kt+1, kt+2) in flight, require stage kt landed.
    if (kt < NKT - 2) {
      stage(kt + 2);
      asm volatile("s_waitcnt vmcnt(12)" ::: "memory");
    } else if (kt == NKT - 2) {
      asm volatile("s_waitcnt vmcnt(6)" ::: "memory");
    } else {
      asm volatile("s_waitcnt vmcnt(0)" ::: "memory");
    }
    __builtin_amdgcn_s_barrier();          // raw barrier: no vmcnt(0) drain
    __builtin_amdgcn_sched_barrier(0);

    const char* ldsA = lds + (kt % 3) * BUFBYTES;
    const char* ldsB = ldsA + ABYTES;

    bf16x8 af[2][4], bv[2][4];
#pragma unroll
    for (int kk = 0; kk < 2; ++kk) {
#pragma unroll
      for (int m = 0; m < 4; ++m) {
        const int row = wr * 64 + m * 16 + l16;
        const int byte = row * 128 + (kk * 32 + lq * 8) * 2;
        af[kk][m] = *(const bf16x8*)(ldsA + (byte ^ swz));
      }
#pragma unroll
      for (int n = 0; n < 4; ++n) {
        const int row = wc * 64 + n * 16 + l16;
        const int byte = row * 128 + (kk * 32 + lq * 8) * 2;
        bv[kk][n] = *(const bf16x8*)(ldsB + (byte ^ swz));
      }
    }

    __builtin_amdgcn_s_setprio(1);
#pragma unroll
    for (int kk = 0; kk < 2; ++kk)
#pragma unroll
      for (int m = 0; m < 4; ++m)
#pragma unroll
        for (int n = 0; n < 4; ++n)
          acc[m][n] = __builtin_amdgcn_mfma_f32_16x16x32_bf16(af[kk][m], bv[kk][n],
                                                              acc[m][n], 0, 0, 0);
    __builtin_amdgcn_s_setprio(0);

    __builtin_amdgcn_sched_barrier(0);
    __builtin_amdgcn_s_barrier();          // protects buffer reuse (kt+3 ≡ kt mod 3)
  }

  // Epilogue: C layout col = l16, row = lq*4 + r (m89-verified). Fuse bias.
  const int lrow = lq * 4;
#pragma unroll
  for (int n = 0; n < 4; ++n) {
    const int col = n0 + wc * 64 + n * 16 + l16;
    const float bvv = bg[col];
#pragma unroll
    for (int m = 0; m < 4; ++m) {
      const int rbase = m0 + wr * 64 + m * 16 + lrow;
#pragma unroll
      for (int r = 0; r < 4; ++r) {
        out[(size_t)(rbase + r) * S_DIM + col] = acc[m][n][r] + bvv;
      }
    }
  }
}

extern "C" void kernel_launch(void* const* d_in, const int* in_sizes, int n_in,
                              void* d_out, int out_size, void* d_ws, size_t ws_size,
                              hipStream_t stream) {
  const float* inp  = (const float*)d_in[0];   // [B, D] f32
  const float* W    = (const float*)d_in[1];   // [N, D] f32
  const float* bias = (const float*)d_in[2];   // [N] f32
  const int*   ids  = (const int*)d_in[3];     // [S] int32
  float* out = (float*)d_out;                  // [B, S] f32

  unsigned short* Wg = (unsigned short*)d_ws;                       // [S,D] bf16 (32 MiB)
  unsigned short* Ab = (unsigned short*)((char*)d_ws +
                        (size_t)S_DIM * D_DIM * 2);                 // [B,D] bf16 (1 MiB)
  float* bg = (float*)((char*)d_ws +
                        (size_t)S_DIM * D_DIM * 2 + (size_t)B_DIM * D_DIM * 2); // [S] f32

  gather_w<<<S_DIM / 4, 256, 0, stream>>>(W, bias, ids, Wg, bg);
  conv_a<<<(B_DIM * D_DIM / 8) / 256, 256, 0, stream>>>(inp, Ab);

  dim3 grid((B_DIM / BM) * (S_DIM / BN));   // 4 * 256 = 1024 blocks
  gemm_bias<<<grid, 512, 0, stream>>>(Ab, Wg, bg, out);
}